// Round 8
// baseline (115.007 us; speedup 1.0000x reference)
//
#include <hip/hip_runtime.h>

#define TOTAL     4194304
#define DIM       32
#define NTOK      (TOTAL / DIM)   // 131072 tokens
#define NCODE     1024
#define DELTA_EPS 2e-3f
#define FLAGBIT   0x40000000

typedef _Float16 half8   __attribute__((ext_vector_type(8)));
typedef float    floatx4 __attribute__((ext_vector_type(4)));

// ---------------- prep: codebook -> f16-hi fragments + (-0.5*|e|^2) + max||e_lo|| ----------
// Fragment slot for code k: step = k>>4, l15 = k&15; slot = step*64 + l4*16 + l15.
// Main reads eh with address (step*64 + lane)*16B -> perfectly coalesced, lane-linear.
__global__ __launch_bounds__(64) void vq_prep(
    const float* __restrict__ cb, float* __restrict__ nhb,
    _Float16* __restrict__ Eh, float* __restrict__ elblk)
{
    const int k = blockIdx.x * 64 + threadIdx.x;   // code id
    const float4* e4 = reinterpret_cast<const float4*>(cb) + (size_t)k * 8;
    float v[DIM];
    float4 t[8];
#pragma unroll
    for (int j = 0; j < 8; ++j) t[j] = e4[j];
#pragma unroll
    for (int j = 0; j < 8; ++j) {
        v[4 * j + 0] = t[j].x; v[4 * j + 1] = t[j].y;
        v[4 * j + 2] = t[j].z; v[4 * j + 3] = t[j].w;
    }
    float e2 = 0.0f;
#pragma unroll
    for (int i = 0; i < DIM; ++i) e2 = fmaf(v[i], v[i], e2);   // sequential: matches rescore
    nhb[k] = -0.5f * e2;

    const int step = k >> 4, l15 = k & 15;
    float el2 = 0.0f;
#pragma unroll
    for (int l4 = 0; l4 < 4; ++l4) {
        half8 h;
#pragma unroll
        for (int j = 0; j < 8; ++j) {
            float x = v[l4 * 8 + j];
            _Float16 hh = (_Float16)x;
            h[j] = hh;
            float lo = x - (float)hh;
            el2 = fmaf(lo, lo, el2);
        }
        const int slot = step * 64 + l4 * 16 + l15;
        *reinterpret_cast<half8*>(Eh + (size_t)slot * 8) = h;
    }
    // block (=wave) max of ||e_lo|| over 64 codes
    float eln = sqrtf(el2);
#pragma unroll
    for (int sh = 1; sh < 64; sh <<= 1) eln = fmaxf(eln, __shfl_xor(eln, sh));
    if (threadIdx.x == 0) elblk[blockIdx.x] = eln;
}

// ---------------- main: barrier-free MFMA argmax + fused exact rescore ----------------
// 1024 blocks x 256 thr; wave owns 32 tokens. eh read straight from global (L2-resident),
// no LDS staging, no __syncthreads -> compiler pipelines loads across steps freely.
__global__ __launch_bounds__(256, 4) void vq_main(
    const float* __restrict__ w, const float* __restrict__ c,
    const float* __restrict__ nhb, const _Float16* __restrict__ Eh,
    const float* __restrict__ elblk, const float* __restrict__ cb,
    int* __restrict__ out)
{
    __shared__ int sOut[128];   // per-wave result scratch (wave-coherent, no barrier)

    const int tid  = threadIdx.x;
    const int lane = tid & 63;
    const int wid  = tid >> 6;
    const int tokw = blockIdx.x * 128 + wid * 32;   // 32 tokens per wave
    const int l15  = lane & 15;
    const int l4   = lane >> 4;

    // uniform max ||e_lo|| over codebook
    float elmax = 0.0f;
#pragma unroll
    for (int b = 0; b < 16; ++b) elmax = fmaxf(elmax, elblk[b]);

    // A fragments: 2 tiles of 16 tokens. A[row=l15][k=l4*8+j]; exact x = xh + xl
    half8 xh[2], xl[2];
    float sqx[2];
#pragma unroll
    for (int m = 0; m < 2; ++m) {
        const int token = tokw + m * 16 + l15;
        const float4* pw = reinterpret_cast<const float4*>(w + (size_t)token * DIM + l4 * 8);
        const float4* pc = reinterpret_cast<const float4*>(c + (size_t)token * DIM + l4 * 8);
        float4 a0 = pw[0], a1 = pw[1], b0 = pc[0], b1 = pc[1];
        float xs[8] = {a0.x - b0.x, a0.y - b0.y, a0.z - b0.z, a0.w - b0.w,
                       a1.x - b1.x, a1.y - b1.y, a1.z - b1.z, a1.w - b1.w};
        float px2 = 0.0f;
#pragma unroll
        for (int j = 0; j < 8; ++j) {
            px2 = fmaf(xs[j], xs[j], px2);
            _Float16 h = (_Float16)xs[j];
            xh[m][j] = h;
            xl[m][j] = (_Float16)(xs[j] - (float)h);
        }
        // full ||x||^2: sum the 4 l4-slices of this token (lanes differing in bits 4,5)
        px2 += __shfl_xor(px2, 16);
        px2 += __shfl_xor(px2, 32);
        sqx[m] = sqrtf(px2);
    }

    const float NEGINF = __uint_as_float(0xFF800000u);
    float best[8], second[8];
#pragma unroll
    for (int q = 0; q < 8; ++q) { best[q] = NEGINF; second[q] = NEGINF; }

    const unsigned ixbase = 1023u - (unsigned)l15;

#pragma unroll 4
    for (int step = 0; step < 64; ++step) {
        const half8 eh = *reinterpret_cast<const half8*>(Eh + (size_t)(step * 64 + lane) * 8);
        const float nh = nhb[step * 16 + l15];
        const unsigned ix = ixbase - (unsigned)(step * 16);
        const floatx4 nv = {nh, nh, nh, nh};
#pragma unroll
        for (int m = 0; m < 2; ++m) {
            floatx4 a = __builtin_amdgcn_mfma_f32_16x16x32_f16(xh[m], eh, nv, 0, 0, 0);
            a = __builtin_amdgcn_mfma_f32_16x16x32_f16(xl[m], eh, a, 0, 0, 0);
#pragma unroll
            for (int r = 0; r < 4; ++r) {
                const int q = m * 4 + r;
                float p = __uint_as_float((__float_as_uint(a[r]) & 0xFFFFFC00u) | ix);
                second[q] = __builtin_amdgcn_fmed3f(p, best[q], second[q]);
                best[q]   = fmaxf(best[q], p);
            }
        }
    }

    // reduce across the 16 code-lanes (xor over lane bits 0..3)
#pragma unroll
    for (int sh = 1; sh < 16; sh <<= 1) {
#pragma unroll
        for (int q = 0; q < 8; ++q) {
            float bB = __shfl_xor(best[q], sh);
            float sB = __shfl_xor(second[q], sh);
            second[q] = fmaxf(fmaxf(second[q], sB), fminf(best[q], bB));
            best[q]   = fmaxf(best[q], bB);
        }
    }

    // per-output-token ||x||: token row = l4*4+r, held (among others) by lane l4*4+r
    float xn[2][4];
#pragma unroll
    for (int m = 0; m < 2; ++m)
#pragma unroll
        for (int r = 0; r < 4; ++r) xn[m][r] = __shfl(sqx[m], l4 * 4 + r);

    if (l15 == 0) {
#pragma unroll
        for (int m = 0; m < 2; ++m) {
#pragma unroll
            for (int r = 0; r < 4; ++r) {
                const int q = m * 4 + r;
                unsigned ub = __float_as_uint(best[q]);
                unsigned us = __float_as_uint(second[q]);
                float bv = __uint_as_float(ub & 0xFFFFFC00u);
                float sv = __uint_as_float(us & 0xFFFFFC00u);
                int eb = (int)((ub >> 23) & 255u);
                int es = (int)((us >> 23) & 255u);
                int em = eb > es ? eb : es;
                em = em > 12 ? em : 12;
                // thr = 4*packing-granule + 2*||x||*elmax + eps
                float thr = __uint_as_float((unsigned)(em - 11) << 23)
                          + 2.0f * xn[m][r] * elmax + DELTA_EPS;
                int k = 1023 - (int)(ub & 1023u);
                sOut[wid * 32 + m * 16 + l4 * 4 + r] = ((bv - sv) < thr) ? (k | FLAGBIT) : k;
            }
        }
    }

    // lane i (<32) owns token tokw+i; rescore flagged tokens exactly (wave-cooperative)
    int myval = 0;
    if (lane < 32) myval = sOut[wid * 32 + lane];
    unsigned long long mask = __ballot(lane < 32 && (myval & FLAGBIT));
    while (mask) {
        const int src = __ffsll(mask) - 1;
        mask &= mask - 1;
        const int token = tokw + src;   // wave-uniform

        float x[DIM];
#pragma unroll
        for (int i = 0; i < DIM; ++i)
            x[i] = w[(size_t)token * DIM + i] - c[(size_t)token * DIM + i];
        float x2 = 0.f;
#pragma unroll
        for (int i = 0; i < DIM; ++i) x2 = fmaf(x[i], x[i], x2);

        float dmin = INFINITY;
        int   kbest = 0;
#pragma unroll 2
        for (int i = 0; i < 16; ++i) {
            const int k = lane + 64 * i;           // ascending per lane
            const float* e = cb + (size_t)k * DIM;
            float dot = 0.f;
#pragma unroll
            for (int j = 0; j < DIM; ++j) dot = fmaf(x[j], e[j], dot);
            float e2 = -2.0f * nhb[k];             // bit-exact |e|^2 (seq-fma in prep)
            float dd = fmaf(-2.0f, dot, x2) + e2;
            if (dd < dmin) { dmin = dd; kbest = k; }
        }
#pragma unroll
        for (int sh = 1; sh < 64; sh <<= 1) {
            float dB = __shfl_xor(dmin, sh);
            int   iB = __shfl_xor(kbest, sh);
            bool take = (dB < dmin) || (dB == dmin && iB < kbest);
            dmin = take ? dB : dmin;
            kbest = take ? iB : kbest;
        }
        if (lane == src) myval = kbest;   // exact index, flag cleared
    }
    if (lane < 32) out[tokw + lane] = myval;   // coalesced 128 B per wave
}

extern "C" void kernel_launch(void* const* d_in, const int* in_sizes, int n_in,
                              void* d_out, int out_size, void* d_ws, size_t ws_size,
                              hipStream_t stream) {
    const float* w  = (const float*)d_in[0];   // weights   [4194304]
    const float* c  = (const float*)d_in[1];   // condition [1,32,131072] flat
    const float* cb = (const float*)d_in[2];   // codebook  [1024,32]
    int* out = (int*)d_out;                    // int32 indices [131072]

    char* wsb = (char*)d_ws;
    float*    nhb   = (float*)wsb;                       // 4 KB
    _Float16* Eh    = (_Float16*)(wsb + 4096);           // 64 KB (fragment-ordered)
    float*    elblk = (float*)(wsb + 4096 + 65536);      // 64 B

    vq_prep<<<NCODE / 64, 64, 0, stream>>>(cb, nhb, Eh, elblk);
    vq_main<<<NTOK / 128, 256, 0, stream>>>(w, c, nhb, Eh, elblk, cb, out);
}

// Round 9
// 106.445 us; speedup vs baseline: 1.0804x; 1.0804x over previous
//
#include <hip/hip_runtime.h>

#define TOTAL     4194304
#define DIM       32
#define NTOK      (TOTAL / DIM)   // 131072 tokens
#define NCODE     1024
#define DELTA_EPS 2e-3f
#define FLAGBIT   0x40000000

typedef _Float16 half8   __attribute__((ext_vector_type(8)));
typedef float    floatx4 __attribute__((ext_vector_type(4)));

#define GLOAD_LDS16(g, l) \
    __builtin_amdgcn_global_load_lds((const __attribute__((address_space(1))) void*)(g), \
                                     (__attribute__((address_space(3))) void*)(l), 16, 0, 0)

// ---------------- prep: codebook -> f16-hi fragments + (-0.5*|e|^2) + max||e_lo|| ----------
// Fragment slot for code k: step = k>>4, l15 = k&15; slot = step*64 + l4*16 + l15.
__global__ __launch_bounds__(64) void vq_prep(
    const float* __restrict__ cb, float* __restrict__ nhb,
    _Float16* __restrict__ Eh, float* __restrict__ elblk)
{
    const int k = blockIdx.x * 64 + threadIdx.x;   // code id
    const float4* e4 = reinterpret_cast<const float4*>(cb) + (size_t)k * 8;
    float v[DIM];
    float4 t[8];
#pragma unroll
    for (int j = 0; j < 8; ++j) t[j] = e4[j];
#pragma unroll
    for (int j = 0; j < 8; ++j) {
        v[4 * j + 0] = t[j].x; v[4 * j + 1] = t[j].y;
        v[4 * j + 2] = t[j].z; v[4 * j + 3] = t[j].w;
    }
    float e2 = 0.0f;
#pragma unroll
    for (int i = 0; i < DIM; ++i) e2 = fmaf(v[i], v[i], e2);   // sequential: matches rescore
    nhb[k] = -0.5f * e2;

    const int step = k >> 4, l15 = k & 15;
    float el2 = 0.0f;
#pragma unroll
    for (int l4 = 0; l4 < 4; ++l4) {
        half8 h;
#pragma unroll
        for (int j = 0; j < 8; ++j) {
            float x = v[l4 * 8 + j];
            _Float16 hh = (_Float16)x;
            h[j] = hh;
            float lo = x - (float)hh;
            el2 = fmaf(lo, lo, el2);
        }
        const int slot = step * 64 + l4 * 16 + l15;
        *reinterpret_cast<half8*>(Eh + (size_t)slot * 8) = h;
    }
    float eln = sqrtf(el2);
#pragma unroll
    for (int sh = 1; sh < 64; sh <<= 1) eln = fmaxf(eln, __shfl_xor(eln, sh));
    if (threadIdx.x == 0) elblk[blockIdx.x] = eln;
}

// ---------------- main: max-TLP MFMA argmax + fused exact rescore ----------------
// 2048 blocks x 256 thr (4 waves); wave owns 16 tokens -> 32 waves/CU resident.
// LDS: 16 KB/chunk staged via global_load_lds; nh from global (L1-resident 4 KB).
__global__ __launch_bounds__(256, 8) void vq_main(
    const float* __restrict__ w, const float* __restrict__ c,
    const float* __restrict__ nhb, const _Float16* __restrict__ Eh,
    const float* __restrict__ elblk, const float* __restrict__ cb,
    int* __restrict__ out)
{
    __shared__ _Float16 sEh[1024 * 8];   // 16 KB: 1024 slots x 16 B
    __shared__ int      sOut[64];        // 16 tokens x 4 waves

    const int tid  = threadIdx.x;
    const int lane = tid & 63;
    const int wid  = tid >> 6;
    const int tokw = blockIdx.x * 64 + wid * 16;   // 16 tokens per wave
    const int l15  = lane & 15;
    const int l4   = lane >> 4;

    // uniform max ||e_lo|| over codebook
    float elmax = 0.0f;
#pragma unroll
    for (int b = 0; b < 16; ++b) elmax = fmaxf(elmax, elblk[b]);

    // A fragment: 1 tile of 16 tokens. A[row=l15][k=l4*8+j]; exact x = xh + xl
    half8 xh, xl;
    float sqx;
    {
        const int token = tokw + l15;
        const float4* pw = reinterpret_cast<const float4*>(w + (size_t)token * DIM + l4 * 8);
        const float4* pc = reinterpret_cast<const float4*>(c + (size_t)token * DIM + l4 * 8);
        float4 a0 = pw[0], a1 = pw[1], b0 = pc[0], b1 = pc[1];
        float xs[8] = {a0.x - b0.x, a0.y - b0.y, a0.z - b0.z, a0.w - b0.w,
                       a1.x - b1.x, a1.y - b1.y, a1.z - b1.z, a1.w - b1.w};
        float px2 = 0.0f;
#pragma unroll
        for (int j = 0; j < 8; ++j) {
            px2 = fmaf(xs[j], xs[j], px2);
            _Float16 h = (_Float16)xs[j];
            xh[j] = h;
            xl[j] = (_Float16)(xs[j] - (float)h);
        }
        px2 += __shfl_xor(px2, 16);
        px2 += __shfl_xor(px2, 32);
        sqx = sqrtf(px2);
    }

    const float NEGINF = __uint_as_float(0xFF800000u);
    float best[4], second[4];
#pragma unroll
    for (int q = 0; q < 4; ++q) { best[q] = NEGINF; second[q] = NEGINF; }

    for (int ch = 0; ch < 4; ++ch) {
        if (ch) __syncthreads();   // all waves done reading previous chunk
        {   // stage 256 codes (16 KB) via async global->LDS, all-linear
            const _Float16* gh = Eh + (size_t)ch * 8192;
#pragma unroll
            for (int r = 0; r < 4; ++r) {
                const int slot = r * 256 + wid * 64;   // wave-uniform base
                GLOAD_LDS16(gh + (size_t)(slot + lane) * 8, sEh + (size_t)slot * 8);
            }
        }
        __syncthreads();   // drain -> staged data visible

        // 16 steps of 16 codes, processed in pairs
#pragma unroll
        for (int sp = 0; sp < 8; ++sp) {
            const int sA = 2 * sp, sB = 2 * sp + 1;
            const half8 ehA = *reinterpret_cast<const half8*>(sEh + (size_t)(sA * 64 + lane) * 8);
            const half8 ehB = *reinterpret_cast<const half8*>(sEh + (size_t)(sB * 64 + lane) * 8);
            const float nhA = nhb[ch * 256 + sA * 16 + l15];   // global, L1-resident
            const float nhB = nhb[ch * 256 + sB * 16 + l15];
            const unsigned ixA = 1023u - (unsigned)(ch * 256 + sA * 16 + l15);
            const unsigned ixB = 1023u - (unsigned)(ch * 256 + sB * 16 + l15);
            const floatx4 nA = {nhA, nhA, nhA, nhA};
            const floatx4 nB = {nhB, nhB, nhB, nhB};
            floatx4 aA = __builtin_amdgcn_mfma_f32_16x16x32_f16(xh, ehA, nA, 0, 0, 0);
            aA = __builtin_amdgcn_mfma_f32_16x16x32_f16(xl, ehA, aA, 0, 0, 0);
            floatx4 aB = __builtin_amdgcn_mfma_f32_16x16x32_f16(xh, ehB, nB, 0, 0, 0);
            aB = __builtin_amdgcn_mfma_f32_16x16x32_f16(xl, ehB, aB, 0, 0, 0);
#pragma unroll
            for (int r = 0; r < 4; ++r) {
                float pA = __uint_as_float((__float_as_uint(aA[r]) & 0xFFFFFC00u) | ixA);
                float pB = __uint_as_float((__float_as_uint(aB[r]) & 0xFFFFFC00u) | ixB);
                // second' = max(second, 2nd-of{pA,pB,best}); best' = max3
                second[r] = fmaxf(second[r], __builtin_amdgcn_fmed3f(pA, pB, best[r]));
                best[r]   = fmaxf(fmaxf(best[r], pA), pB);
            }
        }
    }

    // reduce across the 16 code-lanes (xor over lane bits 0..3)
#pragma unroll
    for (int sh = 1; sh < 16; sh <<= 1) {
#pragma unroll
        for (int q = 0; q < 4; ++q) {
            float bB = __shfl_xor(best[q], sh);
            float sB = __shfl_xor(second[q], sh);
            second[q] = fmaxf(fmaxf(second[q], sB), fminf(best[q], bB));
            best[q]   = fmaxf(best[q], bB);
        }
    }

    // ||x|| for output token row l4*4+r is held by lane (l4*4+r)
    float xn[4];
#pragma unroll
    for (int r = 0; r < 4; ++r) xn[r] = __shfl(sqx, l4 * 4 + r);

    if (l15 == 0) {
#pragma unroll
        for (int r = 0; r < 4; ++r) {
            unsigned ub = __float_as_uint(best[r]);
            unsigned us = __float_as_uint(second[r]);
            float bv = __uint_as_float(ub & 0xFFFFFC00u);
            float sv = __uint_as_float(us & 0xFFFFFC00u);
            int eb = (int)((ub >> 23) & 255u);
            int es = (int)((us >> 23) & 255u);
            int em = eb > es ? eb : es;
            em = em > 12 ? em : 12;
            // thr = 4*packing-granule + 2*||x||*elmax + eps
            float thr = __uint_as_float((unsigned)(em - 11) << 23)
                      + 2.0f * xn[r] * elmax + DELTA_EPS;
            int k = 1023 - (int)(ub & 1023u);
            sOut[wid * 16 + l4 * 4 + r] = ((bv - sv) < thr) ? (k | FLAGBIT) : k;
        }
    }

    // lane i (<16) owns token tokw+i; rescore flagged tokens exactly (wave-cooperative)
    int myval = 0;
    if (lane < 16) myval = sOut[wid * 16 + lane];
    unsigned long long mask = __ballot(lane < 16 && (myval & FLAGBIT));
    while (mask) {
        const int src = __ffsll(mask) - 1;
        mask &= mask - 1;
        const int token = tokw + src;   // wave-uniform

        float x[DIM];
#pragma unroll
        for (int i = 0; i < DIM; ++i)
            x[i] = w[(size_t)token * DIM + i] - c[(size_t)token * DIM + i];
        float x2 = 0.f;
#pragma unroll
        for (int i = 0; i < DIM; ++i) x2 = fmaf(x[i], x[i], x2);

        float dmin = INFINITY;
        int   kbest = 0;
#pragma unroll 2
        for (int i = 0; i < 16; ++i) {
            const int k = lane + 64 * i;           // ascending per lane
            const float* e = cb + (size_t)k * DIM;
            float dot = 0.f;
#pragma unroll
            for (int j = 0; j < DIM; ++j) dot = fmaf(x[j], e[j], dot);
            float e2 = -2.0f * nhb[k];             // bit-exact |e|^2 (seq-fma in prep)
            float dd = fmaf(-2.0f, dot, x2) + e2;
            if (dd < dmin) { dmin = dd; kbest = k; }
        }
#pragma unroll
        for (int sh = 1; sh < 64; sh <<= 1) {
            float dB = __shfl_xor(dmin, sh);
            int   iB = __shfl_xor(kbest, sh);
            bool take = (dB < dmin) || (dB == dmin && iB < kbest);
            dmin = take ? dB : dmin;
            kbest = take ? iB : kbest;
        }
        if (lane == src) myval = kbest;   // exact index, flag cleared
    }
    if (lane < 16) out[tokw + lane] = myval;   // coalesced 64 B per wave
}

extern "C" void kernel_launch(void* const* d_in, const int* in_sizes, int n_in,
                              void* d_out, int out_size, void* d_ws, size_t ws_size,
                              hipStream_t stream) {
    const float* w  = (const float*)d_in[0];   // weights   [4194304]
    const float* c  = (const float*)d_in[1];   // condition [1,32,131072] flat
    const float* cb = (const float*)d_in[2];   // codebook  [1024,32]
    int* out = (int*)d_out;                    // int32 indices [131072]

    char* wsb = (char*)d_ws;
    float*    nhb   = (float*)wsb;                       // 4 KB
    _Float16* Eh    = (_Float16*)(wsb + 4096);           // 64 KB (fragment-ordered)
    float*    elblk = (float*)(wsb + 4096 + 65536);      // 64 B

    vq_prep<<<NCODE / 64, 64, 0, stream>>>(cb, nhb, Eh, elblk);
    vq_main<<<NTOK / 64, 256, 0, stream>>>(w, c, nhb, Eh, elblk, cb, out);
}

// Round 10
// 93.604 us; speedup vs baseline: 1.2287x; 1.1372x over previous
//
#include <hip/hip_runtime.h>

#define TOTAL     4194304
#define DIM       32
#define NTOK      (TOTAL / DIM)   // 131072 tokens
#define NCODE     1024
#define CCODES    512             // codes per chunk (2 chunks)
#define DELTA_EPS 2e-3f
#define FLAGBIT   0x40000000

typedef _Float16 half8   __attribute__((ext_vector_type(8)));
typedef float    floatx4 __attribute__((ext_vector_type(4)));

#define GLOAD_LDS16(g, l) \
    __builtin_amdgcn_global_load_lds((const __attribute__((address_space(1))) void*)(g), \
                                     (__attribute__((address_space(3))) void*)(l), 16, 0, 0)
#define GLOAD_LDS4(g, l) \
    __builtin_amdgcn_global_load_lds((const __attribute__((address_space(1))) void*)(g), \
                                     (__attribute__((address_space(3))) void*)(l), 4, 0, 0)

// ---------------- prep: codebook -> f16-hi fragments + (-0.5*|e|^2) + max||e_lo|| --------
// Fragment slot for code k (512-code chunks): chunk=k>>9, step=(k&511)>>4, l15=k&15;
// slot = chunk*2048 + step*64 + l4*16 + l15 (16 B per slot). Main stages/reads lane-linear.
__global__ __launch_bounds__(64) void vq_prep(
    const float* __restrict__ cb, float* __restrict__ nhb,
    _Float16* __restrict__ Eh, float* __restrict__ elblk)
{
    const int k = blockIdx.x * 64 + threadIdx.x;   // code id
    const float4* e4 = reinterpret_cast<const float4*>(cb) + (size_t)k * 8;
    float v[DIM];
    float4 t[8];
#pragma unroll
    for (int j = 0; j < 8; ++j) t[j] = e4[j];
#pragma unroll
    for (int j = 0; j < 8; ++j) {
        v[4 * j + 0] = t[j].x; v[4 * j + 1] = t[j].y;
        v[4 * j + 2] = t[j].z; v[4 * j + 3] = t[j].w;
    }
    float e2 = 0.0f;
#pragma unroll
    for (int i = 0; i < DIM; ++i) e2 = fmaf(v[i], v[i], e2);   // sequential: matches rescore
    nhb[k] = -0.5f * e2;

    const int chunk = k >> 9, within = k & 511;
    const int step = within >> 4, l15 = within & 15;
    float el2 = 0.0f;
#pragma unroll
    for (int l4 = 0; l4 < 4; ++l4) {
        half8 h;
#pragma unroll
        for (int j = 0; j < 8; ++j) {
            float x = v[l4 * 8 + j];
            _Float16 hh = (_Float16)x;
            h[j] = hh;
            float lo = x - (float)hh;
            el2 = fmaf(lo, lo, el2);
        }
        const int slot = chunk * 2048 + step * 64 + l4 * 16 + l15;
        *reinterpret_cast<half8*>(Eh + (size_t)slot * 8) = h;
    }
    float eln = sqrtf(el2);
#pragma unroll
    for (int sh = 1; sh < 64; sh <<= 1) eln = fmaxf(eln, __shfl_xor(eln, sh));
    if (threadIdx.x == 0) elblk[blockIdx.x] = eln;
}

// ---------------- main: MFMA argmax (Eh-only) + fused exact rescore ----------------
// 1024 blocks x 256 thr; wave owns 32 tokens (m=2). 2 chunks of 512 codes -> 3 barriers.
// LDS 34.8 KB -> 4 blocks/CU (16 waves/CU).
__global__ __launch_bounds__(256) void vq_main(
    const float* __restrict__ w, const float* __restrict__ c,
    const float* __restrict__ nhb, const _Float16* __restrict__ Eh,
    const float* __restrict__ elblk, const float* __restrict__ cb,
    int* __restrict__ out)
{
    __shared__ _Float16 sEh[2048 * 8];   // 32 KB
    __shared__ float    snh[CCODES];     // 2 KB
    __shared__ int      sOut[128];       // 512 B

    const int tid  = threadIdx.x;
    const int lane = tid & 63;
    const int wid  = tid >> 6;
    const int tokw = blockIdx.x * 128 + wid * 32;   // 32 tokens per wave
    const int l15  = lane & 15;
    const int l4   = lane >> 4;

    // uniform max ||e_lo|| over codebook (16 scalar loads)
    float elmax = 0.0f;
#pragma unroll
    for (int b = 0; b < 16; ++b) elmax = fmaxf(elmax, elblk[b]);

    // A fragments: 2 tiles of 16 tokens. A[row=l15][k=l4*8+j]; exact x = xh + xl
    half8 xh[2], xl[2];
    float sqx[2];
#pragma unroll
    for (int m = 0; m < 2; ++m) {
        const int token = tokw + m * 16 + l15;
        const float4* pw = reinterpret_cast<const float4*>(w + (size_t)token * DIM + l4 * 8);
        const float4* pc = reinterpret_cast<const float4*>(c + (size_t)token * DIM + l4 * 8);
        float4 a0 = pw[0], a1 = pw[1], b0 = pc[0], b1 = pc[1];
        float xs[8] = {a0.x - b0.x, a0.y - b0.y, a0.z - b0.z, a0.w - b0.w,
                       a1.x - b1.x, a1.y - b1.y, a1.z - b1.z, a1.w - b1.w};
        float px2 = 0.0f;
#pragma unroll
        for (int j = 0; j < 8; ++j) {
            px2 = fmaf(xs[j], xs[j], px2);
            _Float16 h = (_Float16)xs[j];
            xh[m][j] = h;
            xl[m][j] = (_Float16)(xs[j] - (float)h);
        }
        px2 += __shfl_xor(px2, 16);
        px2 += __shfl_xor(px2, 32);
        sqx[m] = sqrtf(px2);
    }

    const float NEGINF = __uint_as_float(0xFF800000u);
    float best[8], second[8];
#pragma unroll
    for (int q = 0; q < 8; ++q) { best[q] = NEGINF; second[q] = NEGINF; }

    for (int ch = 0; ch < 2; ++ch) {
        if (ch) __syncthreads();   // all waves done with previous chunk before overwrite
        {   // stage 512 codes (32 KB) + snh (2 KB), all-linear async global->LDS
            const _Float16* gh = Eh + (size_t)ch * 16384;
#pragma unroll
            for (int r = 0; r < 8; ++r) {
                const int slot = r * 256 + wid * 64;   // wave-uniform base
                GLOAD_LDS16(gh + (size_t)(slot + lane) * 8, sEh + (size_t)slot * 8);
            }
#pragma unroll
            for (int r = 0; r < 2; ++r)
                GLOAD_LDS4(nhb + ch * CCODES + r * 256 + wid * 64 + lane,
                           snh + r * 256 + wid * 64);
        }
        __syncthreads();   // drain -> staged data visible

        // 32 steps of 16 codes, in pairs (med3 second-tracking); no barriers inside
#pragma unroll 4
        for (int sp = 0; sp < 16; ++sp) {
            const int sA = 2 * sp, sB = 2 * sp + 1;
            const half8 ehA = *reinterpret_cast<const half8*>(sEh + (size_t)(sA * 64 + lane) * 8);
            const half8 ehB = *reinterpret_cast<const half8*>(sEh + (size_t)(sB * 64 + lane) * 8);
            const float nhA = snh[sA * 16 + l15];
            const float nhB = snh[sB * 16 + l15];
            const unsigned ixA = 1023u - (unsigned)(ch * CCODES + sA * 16 + l15);
            const unsigned ixB = ixA - 16u;
            const floatx4 nA = {nhA, nhA, nhA, nhA};
            const floatx4 nB = {nhB, nhB, nhB, nhB};
#pragma unroll
            for (int m = 0; m < 2; ++m) {
                floatx4 aA = __builtin_amdgcn_mfma_f32_16x16x32_f16(xh[m], ehA, nA, 0, 0, 0);
                aA = __builtin_amdgcn_mfma_f32_16x16x32_f16(xl[m], ehA, aA, 0, 0, 0);
                floatx4 aB = __builtin_amdgcn_mfma_f32_16x16x32_f16(xh[m], ehB, nB, 0, 0, 0);
                aB = __builtin_amdgcn_mfma_f32_16x16x32_f16(xl[m], ehB, aB, 0, 0, 0);
#pragma unroll
                for (int r = 0; r < 4; ++r) {
                    const int q = m * 4 + r;
                    float pA = __uint_as_float((__float_as_uint(aA[r]) & 0xFFFFFC00u) | ixA);
                    float pB = __uint_as_float((__float_as_uint(aB[r]) & 0xFFFFFC00u) | ixB);
                    second[q] = fmaxf(second[q], __builtin_amdgcn_fmed3f(pA, pB, best[q]));
                    best[q]   = fmaxf(fmaxf(best[q], pA), pB);
                }
            }
        }
    }

    // reduce across the 16 code-lanes (xor over lane bits 0..3)
#pragma unroll
    for (int sh = 1; sh < 16; sh <<= 1) {
#pragma unroll
        for (int q = 0; q < 8; ++q) {
            float bB = __shfl_xor(best[q], sh);
            float sB = __shfl_xor(second[q], sh);
            second[q] = fmaxf(fmaxf(second[q], sB), fminf(best[q], bB));
            best[q]   = fmaxf(best[q], bB);
        }
    }

    // ||x|| for output token row l4*4+r (held by lane l4*4+r of the m-tile)
    float xn[2][4];
#pragma unroll
    for (int m = 0; m < 2; ++m)
#pragma unroll
        for (int r = 0; r < 4; ++r) xn[m][r] = __shfl(sqx[m], l4 * 4 + r);

    if (l15 == 0) {
#pragma unroll
        for (int m = 0; m < 2; ++m) {
#pragma unroll
            for (int r = 0; r < 4; ++r) {
                const int q = m * 4 + r;
                unsigned ub = __float_as_uint(best[q]);
                unsigned us = __float_as_uint(second[q]);
                float bv = __uint_as_float(ub & 0xFFFFFC00u);
                float sv = __uint_as_float(us & 0xFFFFFC00u);
                int eb = (int)((ub >> 23) & 255u);
                int es = (int)((us >> 23) & 255u);
                int em = eb > es ? eb : es;
                em = em > 12 ? em : 12;
                // thr = 4*packing-granule + 2*||x||*elmax + eps
                float thr = __uint_as_float((unsigned)(em - 11) << 23)
                          + 2.0f * xn[m][r] * elmax + DELTA_EPS;
                int k = 1023 - (int)(ub & 1023u);
                sOut[wid * 32 + m * 16 + l4 * 4 + r] = ((bv - sv) < thr) ? (k | FLAGBIT) : k;
            }
        }
    }

    // lane i (<32) owns token tokw+i; rescore flagged tokens exactly (wave-cooperative)
    int myval = 0;
    if (lane < 32) myval = sOut[wid * 32 + lane];
    unsigned long long mask = __ballot(lane < 32 && (myval & FLAGBIT));
    while (mask) {
        const int src = __ffsll(mask) - 1;
        mask &= mask - 1;
        const int token = tokw + src;   // wave-uniform

        float x[DIM];
#pragma unroll
        for (int i = 0; i < DIM; ++i)
            x[i] = w[(size_t)token * DIM + i] - c[(size_t)token * DIM + i];
        float x2 = 0.f;
#pragma unroll
        for (int i = 0; i < DIM; ++i) x2 = fmaf(x[i], x[i], x2);

        float dmin = INFINITY;
        int   kbest = 0;
#pragma unroll 2
        for (int i = 0; i < 16; ++i) {
            const int k = lane + 64 * i;           // ascending per lane
            const float* e = cb + (size_t)k * DIM;
            float dot = 0.f;
#pragma unroll
            for (int j = 0; j < DIM; ++j) dot = fmaf(x[j], e[j], dot);
            float e2 = -2.0f * nhb[k];             // bit-exact |e|^2 (seq-fma in prep)
            float dd = fmaf(-2.0f, dot, x2) + e2;
            if (dd < dmin) { dmin = dd; kbest = k; }
        }
#pragma unroll
        for (int sh = 1; sh < 64; sh <<= 1) {
            float dB = __shfl_xor(dmin, sh);
            int   iB = __shfl_xor(kbest, sh);
            bool take = (dB < dmin) || (dB == dmin && iB < kbest);
            dmin = take ? dB : dmin;
            kbest = take ? iB : kbest;
        }
        if (lane == src) myval = kbest;   // exact index, flag cleared
    }
    if (lane < 32) out[tokw + lane] = myval;   // coalesced 128 B per wave
}

extern "C" void kernel_launch(void* const* d_in, const int* in_sizes, int n_in,
                              void* d_out, int out_size, void* d_ws, size_t ws_size,
                              hipStream_t stream) {
    const float* w  = (const float*)d_in[0];   // weights   [4194304]
    const float* c  = (const float*)d_in[1];   // condition [1,32,131072] flat
    const float* cb = (const float*)d_in[2];   // codebook  [1024,32]
    int* out = (int*)d_out;                    // int32 indices [131072]

    char* wsb = (char*)d_ws;
    float*    nhb   = (float*)wsb;                       // 4 KB
    _Float16* Eh    = (_Float16*)(wsb + 4096);           // 64 KB (fragment-ordered)
    float*    elblk = (float*)(wsb + 4096 + 65536);      // 64 B

    vq_prep<<<NCODE / 64, 64, 0, stream>>>(cb, nhb, Eh, elblk);
    vq_main<<<NTOK / 128, 256, 0, stream>>>(w, c, nhb, Eh, elblk, cb, out);
}